// Round 18
// baseline (829.866 us; speedup 1.0000x reference)
//
#include <hip/hip_runtime.h>
#include <hip/hip_bf16.h>

typedef __bf16 bf16;
typedef __bf16 bf16x4 __attribute__((ext_vector_type(4)));
typedef __bf16 bf16x8 __attribute__((ext_vector_type(8)));
typedef float f32x4 __attribute__((ext_vector_type(4)));
typedef unsigned int u32;

#define D_    2048
#define NSEQ  4096
#define BATCH 2
#define CH    1024   // recurrence chunk (math is chunk-size invariant)
#define TC    4      // chunks per batch
#define MROWS 8192   // BATCH*NSEQ

__device__ __forceinline__ void gload16(const bf16* g, bf16* l) {
  __builtin_amdgcn_global_load_lds(
      (const __attribute__((address_space(1))) u32*)g,
      (__attribute__((address_space(3))) u32*)l, 16, 0, 0);
}

// ============ 128x256 W-core: counted-vmcnt 2-deep, 2 blocks/CU (proven) ====
//
// Best measured core for this problem (R15/R16: 115 us @ proj shape, 585 TF).
// 8 waves (2M x 4N), per-wave C 64x64 (acc 4x4), BK=32, LDS 48 KB.
// Load audit: 3 loads/thread/tile. Prologue stages t0,t1 (6); vmcnt(3) = t0
// resident. Iter t: reads frags, lgkm(0)+barrier (buffer released), stage
// t+2 into freed buffer, MFMA, counted vmcnt(3) (t+1 resident) + barrier.

struct SmemW {
  alignas(16) bf16 A[2][128 * 32];   // 8 slabs x 512 elems per buffer
  alignas(16) bf16 B[2][256 * 32];   // 16 slabs per buffer
};

__device__ __forceinline__ void stageW(SmemW& sm, int bb, const bf16* A,
                                       int lda, const bf16* B, int ldb,
                                       int k0, int wave, int lane) {
  const int r16 = lane & 15, c8 = lane >> 4;
  gload16(A + (size_t)(wave * 16 + r16) * lda + k0 + c8 * 8,
          &sm.A[bb][wave * 512 + lane * 8]);
#pragma unroll
  for (int j = 0; j < 2; ++j) {
    int nb = 2 * wave + j;
    gload16(B + (size_t)(nb * 16 + r16) * ldb + k0 + c8 * 8,
            &sm.B[bb][nb * 512 + lane * 8]);
  }
}

__device__ __forceinline__ void gemmW_core(SmemW& sm, const bf16* A, int lda,
                                           const bf16* B, int ldb, int K,
                                           f32x4 acc[4][4]) {
  const int tid = threadIdx.x;
  const int wave = tid >> 6, lane = tid & 63;
  const int wr = wave >> 2, wc = wave & 3;
  const int NT = K >> 5;
  if (NT <= 0) return;

  stageW(sm, 0, A, lda, B, ldb, 0, wave, lane);
  if (NT > 1) {
    stageW(sm, 1, A, lda, B, ldb, 32, wave, lane);
    asm volatile("s_waitcnt vmcnt(3)" ::: "memory");  // tile 0 resident (own)
  } else {
    asm volatile("s_waitcnt vmcnt(0)" ::: "memory");
  }
  __builtin_amdgcn_s_barrier();  // tile 0 resident for ALL waves

  const int aoff = wr * 2048 + lane * 8;  // slabs wr*4..+3
  const int boff = wc * 2048 + lane * 8;  // slabs wc*4..+3

  for (int t = 0; t < NT; ++t) {
    const bf16* Ab = sm.A[t & 1];
    const bf16* Bb = sm.B[t & 1];
    bf16x8 av[4], bv[4];
#pragma unroll
    for (int m = 0; m < 4; ++m) av[m] = *(const bf16x8*)&Ab[aoff + m * 512];
#pragma unroll
    for (int n = 0; n < 4; ++n) bv[n] = *(const bf16x8*)&Bb[boff + n * 512];
    asm volatile("s_waitcnt lgkmcnt(0)" ::: "memory");  // my reads done
    __builtin_amdgcn_s_barrier();                       // all waves' reads done
    if (t + 2 < NT)                                     // refill freed buffer
      stageW(sm, t & 1, A, lda, B, ldb, (t + 2) * 32, wave, lane);
    __builtin_amdgcn_s_setprio(1);
#pragma unroll
    for (int m = 0; m < 4; ++m)
#pragma unroll
      for (int n = 0; n < 4; ++n)
        acc[m][n] = __builtin_amdgcn_mfma_f32_16x16x32_bf16(av[m], bv[n],
                                                            acc[m][n], 0, 0, 0);
    __builtin_amdgcn_s_setprio(0);
    if (t + 1 < NT) {
      if (t + 2 < NT)
        asm volatile("s_waitcnt vmcnt(3)" ::: "memory");  // t+1 resident
      else
        asm volatile("s_waitcnt vmcnt(0)" ::: "memory");
      __builtin_amdgcn_s_barrier();
    }
  }
}

#define EPILOGUEW_VARS                             \
  const int lane = threadIdx.x & 63;               \
  const int wave = threadIdx.x >> 6;               \
  const int wr = wave >> 2, wc = wave & 3;         \
  const int l15 = lane & 15, kl = lane >> 4;

// T1: bijective XCD row-chunk swizzle for the (8, 64) big-GEMM grids.
// XCD i owns by in [8i, 8i+8) x all bx -> A working set 4 MB = one L2.
// (R15 measured: FETCH 135 -> 76 MB, dur 137 -> 116 us.)
__device__ __forceinline__ void swzW(int& bx, int& by) {
  int lin = blockIdx.y * gridDim.x + blockIdx.x;   // 0..511
  int xcd = lin & 7, pos = lin >> 3;               // pos 0..63
  by = xcd * 8 + (pos >> 3);
  bx = pos & 7;
}

// ---------------- elementwise kernels ----------------

__global__ __launch_bounds__(256) void k_f2b(const float* __restrict__ in,
                                             bf16* __restrict__ out) {
  int i = (blockIdx.x * 256 + threadIdx.x) * 8;
  float4 a = *(const float4*)(in + i);
  float4 b = *(const float4*)(in + i + 4);
  bf16x8 o;
  o[0] = (bf16)a.x; o[1] = (bf16)a.y; o[2] = (bf16)a.z; o[3] = (bf16)a.w;
  o[4] = (bf16)b.x; o[5] = (bf16)b.y; o[6] = (bf16)b.z; o[7] = (bf16)b.w;
  *(bf16x8*)(out + i) = o;
}

// convert two 2048x2048 fp32 weights into one contiguous bf16 buffer
__global__ __launch_bounds__(256) void k_f2b2(const float* __restrict__ in0,
                                              const float* __restrict__ in1,
                                              bf16* __restrict__ out) {
  int i = (blockIdx.x * 256 + threadIdx.x) * 8;
  const float* src = (i < D_ * D_) ? in0 : in1;
  int off = (i < D_ * D_) ? i : i - D_ * D_;
  float4 a = *(const float4*)(src + off);
  float4 b = *(const float4*)(src + off + 4);
  bf16x8 o;
  o[0] = (bf16)a.x; o[1] = (bf16)a.y; o[2] = (bf16)a.z; o[3] = (bf16)a.w;
  o[4] = (bf16)b.x; o[5] = (bf16)b.y; o[6] = (bf16)b.z; o[7] = (bf16)b.w;
  *(bf16x8*)(out + i) = o;
}

// dst += src (bf16, fp32 add), 8 elems/thread
__global__ __launch_bounds__(256) void k_add(bf16* __restrict__ dst,
                                             const bf16* __restrict__ src) {
  size_t i = ((size_t)blockIdx.x * 256 + threadIdx.x) * 8;
  bf16x8 a = *(const bf16x8*)(dst + i);
  bf16x8 b = *(const bf16x8*)(src + i);
  bf16x8 o;
#pragma unroll
  for (int j = 0; j < 8; ++j) o[j] = (bf16)((float)a[j] + (float)b[j]);
  *(bf16x8*)(dst + i) = o;
}

__global__ __launch_bounds__(256) void k_rms(const float* __restrict__ x,
                                             bf16* __restrict__ xn) {
  const int row = blockIdx.x;
  const int tid = threadIdx.x;
  const float* xr = x + (size_t)row * D_;
  float4 a = *(const float4*)(xr + tid * 8);
  float4 b = *(const float4*)(xr + tid * 8 + 4);
  float ss = a.x * a.x + a.y * a.y + a.z * a.z + a.w * a.w +
             b.x * b.x + b.y * b.y + b.z * b.z + b.w * b.w;
#pragma unroll
  for (int o = 32; o > 0; o >>= 1) ss += __shfl_xor(ss, o, 64);
  __shared__ float red[4];
  if ((tid & 63) == 0) red[tid >> 6] = ss;
  __syncthreads();
  float tot = red[0] + red[1] + red[2] + red[3];
  float sc = rsqrtf(tot * (1.f / D_) + 1.1920928955078125e-07f);
  bf16x8 o;
  o[0] = (bf16)(a.x * sc); o[1] = (bf16)(a.y * sc);
  o[2] = (bf16)(a.z * sc); o[3] = (bf16)(a.w * sc);
  o[4] = (bf16)(b.x * sc); o[5] = (bf16)(b.y * sc);
  o[6] = (bf16)(b.z * sc); o[7] = (bf16)(b.w * sc);
  *(bf16x8*)(xn + (size_t)row * D_ + tid * 8) = o;
}

// ---------------- big dense GEMMs (W-core + XCD swizzle) ----------------
// grid (N/256=8, M/128=64) = 512 blocks -> 2 resident/CU.

// C = act(xn @ W^T); SMODE bit0: store normal, bit1: store transposed [B][D][N]
template <int ACT, int SMODE>
__global__ __launch_bounds__(512, 4) void k_proj2(const bf16* __restrict__ xn,
                                                  const bf16* __restrict__ W,
                                                  bf16* __restrict__ Cn,
                                                  bf16* __restrict__ Ct) {
  __shared__ SmemW sm;
  int bx, by;
  swzW(bx, by);
  const int row0 = by * 128, col0 = bx * 256;
  f32x4 acc[4][4] = {};
  gemmW_core(sm, xn + (size_t)row0 * D_, D_, W + (size_t)col0 * D_, D_, D_, acc);
  EPILOGUEW_VARS
#pragma unroll
  for (int m = 0; m < 4; ++m)
#pragma unroll
    for (int n = 0; n < 4; ++n) {
      const int rb = row0 + wr * 64 + m * 16 + kl * 4;  // 4 consecutive rows
      const int c = col0 + wc * 64 + n * 16 + l15;
      bf16 ob[4];
#pragma unroll
      for (int j = 0; j < 4; ++j) {
        float v = acc[m][n][j];
        if (ACT == 1) v = v / (1.f + __expf(-v));        // silu
        if (ACT == 2) v = 1.f / (1.f + __expf(-v));      // sigmoid
        ob[j] = (bf16)v;
      }
      if (SMODE & 1) {
#pragma unroll
        for (int j = 0; j < 4; ++j) Cn[(size_t)(rb + j) * D_ + c] = ob[j];
      }
      if (SMODE & 2) {
        bf16x4 tv = {ob[0], ob[1], ob[2], ob[3]};
        *(bf16x4*)&Ct[((size_t)(rb >> 12) * D_ + c) * NSEQ + (rb & (NSEQ - 1))] = tv;
      }
    }
}

// out = og @ Wp^T (fp32 store)
__global__ __launch_bounds__(512, 4) void k_final2(const bf16* __restrict__ og,
                                                   const bf16* __restrict__ Wp,
                                                   float* __restrict__ out) {
  __shared__ SmemW sm;
  int bx, by;
  swzW(bx, by);
  const int row0 = by * 128, col0 = bx * 256;
  f32x4 acc[4][4] = {};
  gemmW_core(sm, og + (size_t)row0 * D_, D_, Wp + (size_t)col0 * D_, D_, D_, acc);
  EPILOGUEW_VARS
#pragma unroll
  for (int m = 0; m < 4; ++m)
#pragma unroll
    for (int n = 0; n < 4; ++n)
#pragma unroll
      for (int j = 0; j < 4; ++j) {
        int r = row0 + wr * 64 + m * 16 + kl * 4 + j;
        int c = col0 + wc * 64 + n * 16 + l15;
        out[(size_t)r * D_ + c] = acc[m][n][j];
      }
}

// ---------------- chunked-recurrence kernels (now on the W-core) ------------
// Same math and K-step order as before (fp32 acc over K/32 steps) -> output
// bitwise-identical; only the block tiling changes (128x256, 512 threads).

// s[z] = tril(q_t k_t^T), z = b*TC + t, chunk CH=1024.  grid (4, 8, 8)
__global__ __launch_bounds__(512, 4) void k_scores(const bf16* __restrict__ q,
                                                   const bf16* __restrict__ k,
                                                   bf16* __restrict__ s) {
  const int z = blockIdx.z, b = z >> 2, t = z & 3;
  const int row0 = blockIdx.y * 128, col0 = blockIdx.x * 256;
  if (col0 > row0) return;  // strictly upper tile (col0 mult of 256 >= row0+128)
  __shared__ SmemW sm;
  f32x4 acc[4][4] = {};
  gemmW_core(sm, q + (size_t)(b * NSEQ + t * CH + row0) * D_, D_,
                 k + (size_t)(b * NSEQ + t * CH + col0) * D_, D_, D_, acc);
  EPILOGUEW_VARS
  bf16* sp = s + (size_t)z * CH * CH;
#pragma unroll
  for (int m = 0; m < 4; ++m)
#pragma unroll
    for (int n = 0; n < 4; ++n)
#pragma unroll
      for (int j = 0; j < 4; ++j) {
        int i = row0 + wr * 64 + m * 16 + kl * 4 + j;
        int jc = col0 + wc * 64 + n * 16 + l15;
        float v = (i >= jc) ? acc[m][n][j] : 0.f;
        sp[(size_t)i * CH + jc] = (bf16)v;
      }
}

// og[chunk rows] = s @ v  (intra-chunk; K trimmed to lower-tri extent).
// Chunk 0 gated here; inter-chunk pass skips t=0.  grid (8, 8, 8)
__global__ __launch_bounds__(512, 4) void k_ointra(const bf16* __restrict__ s,
                                                   const bf16* __restrict__ vT,
                                                   const bf16* __restrict__ g,
                                                   bf16* __restrict__ og) {
  __shared__ SmemW sm;
  const int z = blockIdx.z, b = z >> 2, t = z & 3;
  const int row0 = blockIdx.y * 128, col0 = blockIdx.x * 256;
  const int K = row0 + 128;  // only s-cols <= row are nonzero/valid
  f32x4 acc[4][4] = {};
  gemmW_core(sm, s + (size_t)z * CH * CH + (size_t)row0 * CH, CH,
                 vT + (size_t)b * D_ * NSEQ + (size_t)col0 * NSEQ + t * CH, NSEQ,
                 K, acc);
  EPILOGUEW_VARS
  const bool gate0 = (t == 0);
#pragma unroll
  for (int m = 0; m < 4; ++m)
#pragma unroll
    for (int n = 0; n < 4; ++n)
#pragma unroll
      for (int j = 0; j < 4; ++j) {
        int i = row0 + wr * 64 + m * 16 + kl * 4 + j;
        int c = col0 + wc * 64 + n * 16 + l15;
        size_t idx = (size_t)(b * NSEQ + t * CH + i) * D_ + c;
        float v = acc[m][n][j];
        if (gate0) v *= (float)g[idx];
        og[idx] = (bf16)v;
      }
}

// ALL per-chunk outer products in one launch (pure write).  grid (8, 16, 6)
// kv_s[b][e][d] = sum_{j in chunk s} v[j][e] k[j][d], s in {0,1,2}, b in {0,1}.
__global__ __launch_bounds__(512, 4) void k_update_all(const bf16* __restrict__ vT,
                                                       const bf16* __restrict__ kT,
                                                       bf16* __restrict__ kv01,
                                                       bf16* __restrict__ kv2) {
  __shared__ SmemW sm;
  const int z = blockIdx.z, s = z >> 1, b = z & 1;
  const int row0 = blockIdx.y * 128, col0 = blockIdx.x * 256;  // row=e, col=d
  f32x4 acc[4][4] = {};
  gemmW_core(sm, vT + (size_t)b * D_ * NSEQ + (size_t)row0 * NSEQ + s * CH, NSEQ,
                 kT + (size_t)b * D_ * NSEQ + (size_t)col0 * NSEQ + s * CH, NSEQ,
                 CH, acc);
  EPILOGUEW_VARS
  bf16* dst = (s < 2) ? kv01 + (size_t)(s * 2 + b) * D_ * D_
                      : kv2 + (size_t)b * D_ * D_;
#pragma unroll
  for (int m = 0; m < 4; ++m)
#pragma unroll
    for (int n = 0; n < 4; ++n)
#pragma unroll
      for (int j = 0; j < 4; ++j) {
        int e = row0 + wr * 64 + m * 16 + kl * 4 + j;
        int d = col0 + wc * 64 + n * 16 + l15;
        dst[(size_t)e * D_ + d] = (bf16)acc[m][n][j];
      }
}

// og = (og + q_t @ prefix_{t-1}^T) * g  for t in {1,2,3}, both batches.
// grid (8, 8, 6). prefix slots (after in-place k_add prefix sums):
// t=1 -> kv01+b*D^2 ; t=2 -> kv01+(2+b)*D^2 ; t=3 -> kv2+b*D^2.
__global__ __launch_bounds__(512, 4) void k_ointer_all(const bf16* __restrict__ q,
                                                       const bf16* __restrict__ kv01,
                                                       const bf16* __restrict__ kv2,
                                                       const bf16* __restrict__ g,
                                                       bf16* __restrict__ og) {
  __shared__ SmemW sm;
  const int z = blockIdx.z;             // 0..5
  const int t = (z >> 1) + 1, b = z & 1;
  const bf16* kv = (t <= 2) ? kv01 + (size_t)((t - 1) * 2 + b) * D_ * D_
                            : kv2 + (size_t)b * D_ * D_;
  const int row0 = blockIdx.y * 128, col0 = blockIdx.x * 256;
  f32x4 acc[4][4] = {};
  gemmW_core(sm, q + (size_t)(b * NSEQ + t * CH + row0) * D_, D_,
                 kv + (size_t)col0 * D_, D_, D_, acc);
  EPILOGUEW_VARS
#pragma unroll
  for (int m = 0; m < 4; ++m)
#pragma unroll
    for (int n = 0; n < 4; ++n)
#pragma unroll
      for (int j = 0; j < 4; ++j) {
        int i = row0 + wr * 64 + m * 16 + kl * 4 + j;
        int c = col0 + wc * 64 + n * 16 + l15;
        size_t idx = (size_t)(b * NSEQ + t * CH + i) * D_ + c;
        float v = ((float)og[idx] + acc[m][n][j]) * (float)g[idx];
        og[idx] = (bf16)v;
      }
}

// ---------------- host launch ----------------
//
// Workspace plan (~145 MiB, proven): xn/og 32 | kT 32 | vT 32 |
// {k 32 -> kv01 32 (4 slots, EXACT fit)} | shared 16 {Wpair -> s ->
// kv2 (2 slots, EXACT fit) -> Wpb}.  q,g live in d_out.
// Parallel recurrence: scores/ointra -> update_all (pure write) ->
// 2 prefix adds -> ointer_all. All GEMMs on the proven W-core.

extern "C" void kernel_launch(void* const* d_in, const int* in_sizes, int n_in,
                              void* d_out, int out_size, void* d_ws, size_t ws_size,
                              hipStream_t stream) {
  (void)in_sizes; (void)n_in; (void)out_size; (void)ws_size;
  const float* x  = (const float*)d_in[0];
  const float* Wq = (const float*)d_in[1];
  const float* Wk = (const float*)d_in[2];
  const float* Wv = (const float*)d_in[3];
  const float* Wg = (const float*)d_in[4];
  const float* Wp = (const float*)d_in[5];
  float* out = (float*)d_out;

  char* p = (char*)d_ws;
  auto take = [&](size_t bytes) {
    char* r = p;
    p += (bytes + 255) & ~(size_t)255;
    return r;
  };
  const size_t MD2 = (size_t)MROWS * D_ * 2;
  const size_t KV1 = (size_t)D_ * D_;          // elems per kv slot

  bf16* xn  = (bf16*)take(MD2);                        // reused as og
  bf16* kT  = (bf16*)take(MD2);
  bf16* vT  = (bf16*)take(MD2);
  char* kregion = take(MD2);                           // k, then kv01 (4 slots)
  bf16* k    = (bf16*)kregion;
  bf16* kv01 = (bf16*)kregion;
  char* shared = take((size_t)BATCH * TC * CH * CH * 2);  // 16 MiB region
  bf16* Wpair = (bf16*)shared;    // 2 weights, then s, then kv2 (2 slots), then Wp
  bf16* s    = (bf16*)shared;
  bf16* kv2  = (bf16*)shared;
  bf16* og = xn;

  bf16* q = (bf16*)d_out;
  bf16* g = (bf16*)d_out + (size_t)MROWS * D_;

  const size_t W1 = (size_t)D_ * D_;
  dim3 gpW(D_ / 256, MROWS / 128);  // (8, 64) = 512 blocks, 2/CU

  k_rms<<<MROWS, 256, 0, stream>>>(x, xn);

  k_f2b2<<<2 * (D_ * D_) / 2048, 256, 0, stream>>>(Wq, Wk, Wpair);
  k_proj2<1, 1><<<gpW, 512, 0, stream>>>(xn, Wpair, q, (bf16*)nullptr);
  k_proj2<1, 3><<<gpW, 512, 0, stream>>>(xn, Wpair + W1, k, kT);
  k_f2b2<<<2 * (D_ * D_) / 2048, 256, 0, stream>>>(Wv, Wg, Wpair);
  k_proj2<1, 2><<<gpW, 512, 0, stream>>>(xn, Wpair, (bf16*)nullptr, vT);
  k_proj2<2, 1><<<gpW, 512, 0, stream>>>(xn, Wpair + W1, g, (bf16*)nullptr);

  // intra-chunk: masked scores (lower-tri tiles only) then s @ v
  // (chunk 0 gated inside ointra; no inter-chunk pass for t=0)
  k_scores<<<dim3(CH / 256, CH / 128, BATCH * TC), 512, 0, stream>>>(q, k, s);
  k_ointra<<<dim3(D_ / 256, CH / 128, BATCH * TC), 512, 0, stream>>>(s, vT, g, og);

  // k and s dead -> their regions hold the 6 kv slots. All outer products
  // in ONE launch, then in-place prefix sums, then all inter-chunk GEMMs
  // in ONE launch.
  k_update_all<<<dim3(D_ / 256, D_ / 128, 6), 512, 0, stream>>>(vT, kT, kv01, kv2);
  k_add<<<(2 * D_ * D_) / 2048, 256, 0, stream>>>(kv01 + 2 * KV1, kv01);  // s1 += s0
  k_add<<<(2 * D_ * D_) / 2048, 256, 0, stream>>>(kv2, kv01 + 2 * KV1);   // s2 += s1
  k_ointer_all<<<dim3(D_ / 256, CH / 128, 6), 512, 0, stream>>>(q, kv01, kv2,
                                                                g, og);

  // kv slots dead; shared region hosts the bf16 Wp
  bf16* Wpb = (bf16*)shared;
  k_f2b<<<(D_ * D_) / 2048, 256, 0, stream>>>(Wp, Wpb);
  k_final2<<<gpW, 512, 0, stream>>>(og, Wpb, out);
}

// Round 19
// 766.838 us; speedup vs baseline: 1.0822x; 1.0822x over previous
//
#include <hip/hip_runtime.h>
#include <hip/hip_bf16.h>

typedef __bf16 bf16;
typedef __bf16 bf16x4 __attribute__((ext_vector_type(4)));
typedef __bf16 bf16x8 __attribute__((ext_vector_type(8)));
typedef float f32x4 __attribute__((ext_vector_type(4)));
typedef unsigned int u32;

#define D_    2048
#define NSEQ  4096
#define BATCH 2
#define CH    1024   // recurrence chunk (math is chunk-size invariant)
#define TC    4      // chunks per batch
#define MROWS 8192   // BATCH*NSEQ

__device__ __forceinline__ void gload16(const bf16* g, bf16* l) {
  __builtin_amdgcn_global_load_lds(
      (const __attribute__((address_space(1))) u32*)g,
      (__attribute__((address_space(3))) u32*)l, 16, 0, 0);
}

// ============ 128^2 core, minimal 2-phase (recurrence kernels; proven) ======
// R18 lesson: this core BEATS the W-core at the recurrence shapes (more
// blocks, better cross-block overlap, shallower pipeline for small K).

struct SmemTiles {
  alignas(16) bf16 As[2][128 * 32];
  alignas(16) bf16 Bs[2][128 * 32];
};

__device__ __forceinline__ void stage128(SmemTiles& sm, int bb, const bf16* A,
                                         int lda, const bf16* B, int ldb,
                                         int k0, int tid) {
#pragma unroll
  for (int it = 0; it < 2; ++it) {
    int c = it * 256 + tid;      // 16B chunk index, 512 chunks per tile
    int r = c >> 2;              // 4 chunks per 32-elem row
    int co = (c & 3) << 3;
    gload16(A + (size_t)r * lda + k0 + co, &sm.As[bb][c * 8]);
    gload16(B + (size_t)r * ldb + k0 + co, &sm.Bs[bb][c * 8]);
  }
}

__device__ __forceinline__ void gemm_core(SmemTiles& sm, const bf16* A, int lda,
                                          const bf16* B, int ldb, int K,
                                          f32x4 acc[4][4]) {
  const int tid = threadIdx.x;
  const int lane = tid & 63;
  const int wave = tid >> 6;
  const int wr = wave >> 1, wc = wave & 1;
  const int l15 = lane & 15, kl = lane >> 4;
  const int NT = K >> 5;
  if (NT <= 0) return;

  stage128(sm, 0, A, lda, B, ldb, 0, tid);
  __syncthreads();

  const int ao = (wr * 64 + l15) * 32 + kl * 8;
  const int bo = (wc * 64 + l15) * 32 + kl * 8;

  for (int t = 0; t < NT; ++t) {
    if (t + 1 < NT)
      stage128(sm, (t + 1) & 1, A, lda, B, ldb, (t + 1) * 32, tid);
    const bf16* Ab = sm.As[t & 1];
    const bf16* Bb = sm.Bs[t & 1];
    bf16x8 a[4], b[4];
#pragma unroll
    for (int m = 0; m < 4; ++m) a[m] = *(const bf16x8*)(Ab + ao + m * 16 * 32);
#pragma unroll
    for (int n = 0; n < 4; ++n) b[n] = *(const bf16x8*)(Bb + bo + n * 16 * 32);
    __builtin_amdgcn_s_setprio(1);
#pragma unroll
    for (int m = 0; m < 4; ++m)
#pragma unroll
      for (int n = 0; n < 4; ++n)
        acc[m][n] = __builtin_amdgcn_mfma_f32_16x16x32_bf16(a[m], b[n], acc[m][n], 0, 0, 0);
    __builtin_amdgcn_s_setprio(0);
    if (t + 1 < NT) __syncthreads();
  }
}

#define EPILOGUE_VARS                              \
  const int lane = threadIdx.x & 63;               \
  const int wave = threadIdx.x >> 6;               \
  const int wr = wave >> 1, wc = wave & 1;         \
  const int l15 = lane & 15, kl = lane >> 4;

// ============ 128x256 big-GEMM core: counted-vmcnt 2-deep (proven best) =====

struct SmemW {
  alignas(16) bf16 A[2][128 * 32];   // 8 slabs x 512 elems per buffer
  alignas(16) bf16 B[2][256 * 32];   // 16 slabs per buffer
};

__device__ __forceinline__ void stageW(SmemW& sm, int bb, const bf16* A,
                                       int lda, const bf16* B, int ldb,
                                       int k0, int wave, int lane) {
  const int r16 = lane & 15, c8 = lane >> 4;
  gload16(A + (size_t)(wave * 16 + r16) * lda + k0 + c8 * 8,
          &sm.A[bb][wave * 512 + lane * 8]);
#pragma unroll
  for (int j = 0; j < 2; ++j) {
    int nb = 2 * wave + j;
    gload16(B + (size_t)(nb * 16 + r16) * ldb + k0 + c8 * 8,
            &sm.B[bb][nb * 512 + lane * 8]);
  }
}

__device__ __forceinline__ void gemmW_core(SmemW& sm, const bf16* A, int lda,
                                           const bf16* B, int ldb, int K,
                                           f32x4 acc[4][4]) {
  const int tid = threadIdx.x;
  const int wave = tid >> 6, lane = tid & 63;
  const int wr = wave >> 2, wc = wave & 3;
  const int NT = K >> 5;
  if (NT <= 0) return;

  stageW(sm, 0, A, lda, B, ldb, 0, wave, lane);
  if (NT > 1) {
    stageW(sm, 1, A, lda, B, ldb, 32, wave, lane);
    asm volatile("s_waitcnt vmcnt(3)" ::: "memory");  // tile 0 resident (own)
  } else {
    asm volatile("s_waitcnt vmcnt(0)" ::: "memory");
  }
  __builtin_amdgcn_s_barrier();  // tile 0 resident for ALL waves

  const int aoff = wr * 2048 + lane * 8;  // slabs wr*4..+3
  const int boff = wc * 2048 + lane * 8;  // slabs wc*4..+3

  for (int t = 0; t < NT; ++t) {
    const bf16* Ab = sm.A[t & 1];
    const bf16* Bb = sm.B[t & 1];
    bf16x8 av[4], bv[4];
#pragma unroll
    for (int m = 0; m < 4; ++m) av[m] = *(const bf16x8*)&Ab[aoff + m * 512];
#pragma unroll
    for (int n = 0; n < 4; ++n) bv[n] = *(const bf16x8*)&Bb[boff + n * 512];
    asm volatile("s_waitcnt lgkmcnt(0)" ::: "memory");  // my reads done
    __builtin_amdgcn_s_barrier();                       // all waves' reads done
    if (t + 2 < NT)                                     // refill freed buffer
      stageW(sm, t & 1, A, lda, B, ldb, (t + 2) * 32, wave, lane);
    __builtin_amdgcn_s_setprio(1);
#pragma unroll
    for (int m = 0; m < 4; ++m)
#pragma unroll
      for (int n = 0; n < 4; ++n)
        acc[m][n] = __builtin_amdgcn_mfma_f32_16x16x32_bf16(av[m], bv[n],
                                                            acc[m][n], 0, 0, 0);
    __builtin_amdgcn_s_setprio(0);
    if (t + 1 < NT) {
      if (t + 2 < NT)
        asm volatile("s_waitcnt vmcnt(3)" ::: "memory");  // t+1 resident
      else
        asm volatile("s_waitcnt vmcnt(0)" ::: "memory");
      __builtin_amdgcn_s_barrier();
    }
  }
}

#define EPILOGUEW_VARS                             \
  const int lane = threadIdx.x & 63;               \
  const int wave = threadIdx.x >> 6;               \
  const int wr = wave >> 2, wc = wave & 3;         \
  const int l15 = lane & 15, kl = lane >> 4;

// T1: bijective XCD row-chunk swizzle for the (8, 64) big-GEMM grids.
// XCD i owns by in [8i, 8i+8) x all bx -> A working set 4 MB = one L2.
// (R15 measured: FETCH 135 -> 76 MB, dur 137 -> 116 us.)
__device__ __forceinline__ void swzW(int& bx, int& by) {
  int lin = blockIdx.y * gridDim.x + blockIdx.x;   // 0..511
  int xcd = lin & 7, pos = lin >> 3;               // pos 0..63
  by = xcd * 8 + (pos >> 3);
  bx = pos & 7;
}

// ---------------- elementwise kernels ----------------

__global__ __launch_bounds__(256) void k_f2b(const float* __restrict__ in,
                                             bf16* __restrict__ out) {
  int i = (blockIdx.x * 256 + threadIdx.x) * 8;
  float4 a = *(const float4*)(in + i);
  float4 b = *(const float4*)(in + i + 4);
  bf16x8 o;
  o[0] = (bf16)a.x; o[1] = (bf16)a.y; o[2] = (bf16)a.z; o[3] = (bf16)a.w;
  o[4] = (bf16)b.x; o[5] = (bf16)b.y; o[6] = (bf16)b.z; o[7] = (bf16)b.w;
  *(bf16x8*)(out + i) = o;
}

// convert two 2048x2048 fp32 weights into one contiguous bf16 buffer
__global__ __launch_bounds__(256) void k_f2b2(const float* __restrict__ in0,
                                              const float* __restrict__ in1,
                                              bf16* __restrict__ out) {
  int i = (blockIdx.x * 256 + threadIdx.x) * 8;
  const float* src = (i < D_ * D_) ? in0 : in1;
  int off = (i < D_ * D_) ? i : i - D_ * D_;
  float4 a = *(const float4*)(src + off);
  float4 b = *(const float4*)(src + off + 4);
  bf16x8 o;
  o[0] = (bf16)a.x; o[1] = (bf16)a.y; o[2] = (bf16)a.z; o[3] = (bf16)a.w;
  o[4] = (bf16)b.x; o[5] = (bf16)b.y; o[6] = (bf16)b.z; o[7] = (bf16)b.w;
  *(bf16x8*)(out + i) = o;
}

// fused prefix adds over the kv slots: s1 += s0 ; s2 += (s1+s0).
// Element order per output identical to the two sequential k_add launches.
__global__ __launch_bounds__(256) void k_add2(bf16* __restrict__ s0,
                                              bf16* __restrict__ s1,
                                              bf16* __restrict__ s2) {
  size_t i = ((size_t)blockIdx.x * 256 + threadIdx.x) * 8;
  bf16x8 a = *(const bf16x8*)(s0 + i);
  bf16x8 b = *(const bf16x8*)(s1 + i);
  bf16x8 c = *(const bf16x8*)(s2 + i);
  bf16x8 o1, o2;
#pragma unroll
  for (int j = 0; j < 8; ++j) {
    float p = (float)a[j] + (float)b[j];
    o1[j] = (bf16)p;
    o2[j] = (bf16)((float)o1[j] + (float)c[j]);
  }
  *(bf16x8*)(s1 + i) = o1;
  *(bf16x8*)(s2 + i) = o2;
}

__global__ __launch_bounds__(256) void k_rms(const float* __restrict__ x,
                                             bf16* __restrict__ xn) {
  const int row = blockIdx.x;
  const int tid = threadIdx.x;
  const float* xr = x + (size_t)row * D_;
  float4 a = *(const float4*)(xr + tid * 8);
  float4 b = *(const float4*)(xr + tid * 8 + 4);
  float ss = a.x * a.x + a.y * a.y + a.z * a.z + a.w * a.w +
             b.x * b.x + b.y * b.y + b.z * b.z + b.w * b.w;
#pragma unroll
  for (int o = 32; o > 0; o >>= 1) ss += __shfl_xor(ss, o, 64);
  __shared__ float red[4];
  if ((tid & 63) == 0) red[tid >> 6] = ss;
  __syncthreads();
  float tot = red[0] + red[1] + red[2] + red[3];
  float sc = rsqrtf(tot * (1.f / D_) + 1.1920928955078125e-07f);
  bf16x8 o;
  o[0] = (bf16)(a.x * sc); o[1] = (bf16)(a.y * sc);
  o[2] = (bf16)(a.z * sc); o[3] = (bf16)(a.w * sc);
  o[4] = (bf16)(b.x * sc); o[5] = (bf16)(b.y * sc);
  o[6] = (bf16)(b.z * sc); o[7] = (bf16)(b.w * sc);
  *(bf16x8*)(xn + (size_t)row * D_ + tid * 8) = o;
}

// ---------------- big dense GEMMs (W-core + XCD swizzle) ----------------
// grid (N/256=8, M/128=64) = 512 blocks -> 2 resident/CU.

// C = act(xn @ W^T); SMODE bit0: store normal, bit1: store transposed [B][D][N]
template <int ACT, int SMODE>
__global__ __launch_bounds__(512, 4) void k_proj2(const bf16* __restrict__ xn,
                                                  const bf16* __restrict__ W,
                                                  bf16* __restrict__ Cn,
                                                  bf16* __restrict__ Ct) {
  __shared__ SmemW sm;
  int bx, by;
  swzW(bx, by);
  const int row0 = by * 128, col0 = bx * 256;
  f32x4 acc[4][4] = {};
  gemmW_core(sm, xn + (size_t)row0 * D_, D_, W + (size_t)col0 * D_, D_, D_, acc);
  EPILOGUEW_VARS
#pragma unroll
  for (int m = 0; m < 4; ++m)
#pragma unroll
    for (int n = 0; n < 4; ++n) {
      const int rb = row0 + wr * 64 + m * 16 + kl * 4;  // 4 consecutive rows
      const int c = col0 + wc * 64 + n * 16 + l15;
      bf16 ob[4];
#pragma unroll
      for (int j = 0; j < 4; ++j) {
        float v = acc[m][n][j];
        if (ACT == 1) v = v / (1.f + __expf(-v));        // silu
        if (ACT == 2) v = 1.f / (1.f + __expf(-v));      // sigmoid
        ob[j] = (bf16)v;
      }
      if (SMODE & 1) {
#pragma unroll
        for (int j = 0; j < 4; ++j) Cn[(size_t)(rb + j) * D_ + c] = ob[j];
      }
      if (SMODE & 2) {
        bf16x4 tv = {ob[0], ob[1], ob[2], ob[3]};
        *(bf16x4*)&Ct[((size_t)(rb >> 12) * D_ + c) * NSEQ + (rb & (NSEQ - 1))] = tv;
      }
    }
}

// out = og @ Wp^T (fp32 store)
__global__ __launch_bounds__(512, 4) void k_final2(const bf16* __restrict__ og,
                                                   const bf16* __restrict__ Wp,
                                                   float* __restrict__ out) {
  __shared__ SmemW sm;
  int bx, by;
  swzW(bx, by);
  const int row0 = by * 128, col0 = bx * 256;
  f32x4 acc[4][4] = {};
  gemmW_core(sm, og + (size_t)row0 * D_, D_, Wp + (size_t)col0 * D_, D_, D_, acc);
  EPILOGUEW_VARS
#pragma unroll
  for (int m = 0; m < 4; ++m)
#pragma unroll
    for (int n = 0; n < 4; ++n)
#pragma unroll
      for (int j = 0; j < 4; ++j) {
        int r = row0 + wr * 64 + m * 16 + kl * 4 + j;
        int c = col0 + wc * 64 + n * 16 + l15;
        out[(size_t)r * D_ + c] = acc[m][n][j];
      }
}

// ---------------- chunked-recurrence kernels (128^2 core, R16-proven) -------

// s[z] = tril(q_t k_t^T), z = b*TC + t, chunk CH=1024.
__global__ __launch_bounds__(256) void k_scores(const bf16* __restrict__ q,
                                                const bf16* __restrict__ k,
                                                bf16* __restrict__ s) {
  const int z = blockIdx.z, b = z >> 2, t = z & 3;
  const int row0 = blockIdx.y * 128, col0 = blockIdx.x * 128;
  if (col0 > row0) return;  // strictly upper tile
  __shared__ SmemTiles sm;
  f32x4 acc[4][4] = {};
  gemm_core(sm, q + (size_t)(b * NSEQ + t * CH + row0) * D_, D_,
                k + (size_t)(b * NSEQ + t * CH + col0) * D_, D_, D_, acc);
  EPILOGUE_VARS
  bf16* sp = s + (size_t)z * CH * CH;
#pragma unroll
  for (int m = 0; m < 4; ++m)
#pragma unroll
    for (int n = 0; n < 4; ++n)
#pragma unroll
      for (int j = 0; j < 4; ++j) {
        int i = row0 + wr * 64 + m * 16 + kl * 4 + j;
        int jc = col0 + wc * 64 + n * 16 + l15;
        float v = (i >= jc) ? acc[m][n][j] : 0.f;
        sp[(size_t)i * CH + jc] = (bf16)v;
      }
}

// og[chunk rows] = s @ v  (intra-chunk; K trimmed to lower-tri extent).
// Chunk 0 gated here; inter-chunk pass skips t=0.
__global__ __launch_bounds__(256) void k_ointra(const bf16* __restrict__ s,
                                                const bf16* __restrict__ vT,
                                                const bf16* __restrict__ g,
                                                bf16* __restrict__ og) {
  __shared__ SmemTiles sm;
  const int z = blockIdx.z, b = z >> 2, t = z & 3;
  const int row0 = blockIdx.y * 128, col0 = blockIdx.x * 128;
  const int K = row0 + 128;
  f32x4 acc[4][4] = {};
  gemm_core(sm, s + (size_t)z * CH * CH + (size_t)row0 * CH, CH,
                vT + (size_t)b * D_ * NSEQ + (size_t)col0 * NSEQ + t * CH, NSEQ,
                K, acc);
  EPILOGUE_VARS
  const bool gate0 = (t == 0);
#pragma unroll
  for (int m = 0; m < 4; ++m)
#pragma unroll
    for (int n = 0; n < 4; ++n)
#pragma unroll
      for (int j = 0; j < 4; ++j) {
        int i = row0 + wr * 64 + m * 16 + kl * 4 + j;
        int c = col0 + wc * 64 + n * 16 + l15;
        size_t idx = (size_t)(b * NSEQ + t * CH + i) * D_ + c;
        float v = acc[m][n][j];
        if (gate0) v *= (float)g[idx];
        og[idx] = (bf16)v;
      }
}

// ALL per-chunk outer products in one parallel launch (pure write):
// kv_s[b][e][d] = sum_{j in chunk s} v[j][e] k[j][d], s in {0,1,2}, b in {0,1}.
// Slots: s<2 -> kv01 + (s*2+b)*D^2 ; s==2 -> kv2 + b*D^2.
__global__ __launch_bounds__(256) void k_update_all(const bf16* __restrict__ vT,
                                                    const bf16* __restrict__ kT,
                                                    bf16* __restrict__ kv01,
                                                    bf16* __restrict__ kv2) {
  __shared__ SmemTiles sm;
  const int z = blockIdx.z, s = z >> 1, b = z & 1;
  const int row0 = blockIdx.y * 128, col0 = blockIdx.x * 128;  // row=e, col=d
  f32x4 acc[4][4] = {};
  gemm_core(sm, vT + (size_t)b * D_ * NSEQ + (size_t)row0 * NSEQ + s * CH, NSEQ,
                kT + (size_t)b * D_ * NSEQ + (size_t)col0 * NSEQ + s * CH, NSEQ,
                CH, acc);
  EPILOGUE_VARS
  bf16* dst = (s < 2) ? kv01 + (size_t)(s * 2 + b) * D_ * D_
                      : kv2 + (size_t)b * D_ * D_;
#pragma unroll
  for (int m = 0; m < 4; ++m)
#pragma unroll
    for (int n = 0; n < 4; ++n)
#pragma unroll
      for (int j = 0; j < 4; ++j) {
        int e = row0 + wr * 64 + m * 16 + kl * 4 + j;
        int d = col0 + wc * 64 + n * 16 + l15;
        dst[(size_t)e * D_ + d] = (bf16)acc[m][n][j];
      }
}

// og = (og + q_t @ prefix_{t-1}^T) * g  for all t in {1,2,3}, both batches,
// one parallel launch. prefix slots (after k_add2 prefix sums):
// t=1 -> kv01+b*D^2 ; t=2 -> kv01+(2+b)*D^2 ; t=3 -> kv2+b*D^2.
__global__ __launch_bounds__(256) void k_ointer_all(const bf16* __restrict__ q,
                                                    const bf16* __restrict__ kv01,
                                                    const bf16* __restrict__ kv2,
                                                    const bf16* __restrict__ g,
                                                    bf16* __restrict__ og) {
  __shared__ SmemTiles sm;
  const int z = blockIdx.z;             // 0..5
  const int t = (z >> 1) + 1, b = z & 1;
  const bf16* kv = (t <= 2) ? kv01 + (size_t)((t - 1) * 2 + b) * D_ * D_
                            : kv2 + (size_t)b * D_ * D_;
  const int row0 = blockIdx.y * 128, col0 = blockIdx.x * 128;
  f32x4 acc[4][4] = {};
  gemm_core(sm, q + (size_t)(b * NSEQ + t * CH + row0) * D_, D_,
                kv + (size_t)col0 * D_, D_, D_, acc);
  EPILOGUE_VARS
#pragma unroll
  for (int m = 0; m < 4; ++m)
#pragma unroll
    for (int n = 0; n < 4; ++n)
#pragma unroll
      for (int j = 0; j < 4; ++j) {
        int i = row0 + wr * 64 + m * 16 + kl * 4 + j;
        int c = col0 + wc * 64 + n * 16 + l15;
        size_t idx = (size_t)(b * NSEQ + t * CH + i) * D_ + c;
        float v = ((float)og[idx] + acc[m][n][j]) * (float)g[idx];
        og[idx] = (bf16)v;
      }
}

// ---------------- host launch ----------------
//
// Workspace plan (~145 MiB, proven): xn/og 32 | kT 32 | vT 32 |
// {k 32 -> kv01 32 (4 slots, EXACT fit)} | shared 16 {Wpair -> s ->
// kv2 (2 slots, EXACT fit) -> Wpb}.  q,g live in d_out.
// Parallel recurrence: scores/ointra -> update_all (pure write) ->
// fused prefix add -> ointer_all.  (R16 config + k_add2.)

extern "C" void kernel_launch(void* const* d_in, const int* in_sizes, int n_in,
                              void* d_out, int out_size, void* d_ws, size_t ws_size,
                              hipStream_t stream) {
  (void)in_sizes; (void)n_in; (void)out_size; (void)ws_size;
  const float* x  = (const float*)d_in[0];
  const float* Wq = (const float*)d_in[1];
  const float* Wk = (const float*)d_in[2];
  const float* Wv = (const float*)d_in[3];
  const float* Wg = (const float*)d_in[4];
  const float* Wp = (const float*)d_in[5];
  float* out = (float*)d_out;

  char* p = (char*)d_ws;
  auto take = [&](size_t bytes) {
    char* r = p;
    p += (bytes + 255) & ~(size_t)255;
    return r;
  };
  const size_t MD2 = (size_t)MROWS * D_ * 2;
  const size_t KV1 = (size_t)D_ * D_;          // elems per kv slot

  bf16* xn  = (bf16*)take(MD2);                        // reused as og
  bf16* kT  = (bf16*)take(MD2);
  bf16* vT  = (bf16*)take(MD2);
  char* kregion = take(MD2);                           // k, then kv01 (4 slots)
  bf16* k    = (bf16*)kregion;
  bf16* kv01 = (bf16*)kregion;
  char* shared = take((size_t)BATCH * TC * CH * CH * 2);  // 16 MiB region
  bf16* Wpair = (bf16*)shared;    // 2 weights, then s, then kv2 (2 slots), then Wp
  bf16* s    = (bf16*)shared;
  bf16* kv2  = (bf16*)shared;
  bf16* og = xn;

  bf16* q = (bf16*)d_out;
  bf16* g = (bf16*)d_out + (size_t)MROWS * D_;

  const size_t W1 = (size_t)D_ * D_;
  dim3 gpW(D_ / 256, MROWS / 128);  // (8, 64) = 512 blocks, 2/CU

  k_rms<<<MROWS, 256, 0, stream>>>(x, xn);

  k_f2b2<<<2 * (D_ * D_) / 2048, 256, 0, stream>>>(Wq, Wk, Wpair);
  k_proj2<1, 1><<<gpW, 512, 0, stream>>>(xn, Wpair, q, (bf16*)nullptr);
  k_proj2<1, 3><<<gpW, 512, 0, stream>>>(xn, Wpair + W1, k, kT);
  k_f2b2<<<2 * (D_ * D_) / 2048, 256, 0, stream>>>(Wv, Wg, Wpair);
  k_proj2<1, 2><<<gpW, 512, 0, stream>>>(xn, Wpair, (bf16*)nullptr, vT);
  k_proj2<2, 1><<<gpW, 512, 0, stream>>>(xn, Wpair + W1, g, (bf16*)nullptr);

  // intra-chunk: masked scores (lower-tri tiles only) then s @ v
  // (chunk 0 gated inside ointra; no inter-chunk pass for t=0)
  k_scores<<<dim3(CH / 128, CH / 128, BATCH * TC), 256, 0, stream>>>(q, k, s);
  k_ointra<<<dim3(D_ / 128, CH / 128, BATCH * TC), 256, 0, stream>>>(s, vT, g, og);

  // k and s dead -> their regions hold the 6 kv slots. All outer products
  // in ONE launch (grid 1536), then one fused prefix-add, then all
  // inter-chunk GEMMs in ONE launch (grid 768).
  k_update_all<<<dim3(D_ / 128, D_ / 128, 6), 256, 0, stream>>>(vT, kT, kv01, kv2);
  k_add2<<<(2 * D_ * D_) / 2048, 256, 0, stream>>>(kv01, kv01 + 2 * KV1, kv2);
  k_ointer_all<<<dim3(D_ / 128, CH / 128, 6), 256, 0, stream>>>(q, kv01, kv2,
                                                                g, og);

  // kv slots dead; shared region hosts the bf16 Wp
  bf16* Wpb = (bf16*)shared;
  k_f2b<<<(D_ * D_) / 2048, 256, 0, stream>>>(Wp, Wpb);
  k_final2<<<gpW, 512, 0, stream>>>(og, Wpb, out);
}

// Round 20
// 761.593 us; speedup vs baseline: 1.0896x; 1.0069x over previous
//
#include <hip/hip_runtime.h>
#include <hip/hip_bf16.h>

typedef __bf16 bf16;
typedef __bf16 bf16x4 __attribute__((ext_vector_type(4)));
typedef __bf16 bf16x8 __attribute__((ext_vector_type(8)));
typedef float f32x4 __attribute__((ext_vector_type(4)));
typedef unsigned int u32;

#define D_    2048
#define NSEQ  4096
#define BATCH 2
#define CH    1024   // recurrence chunk (math is chunk-size invariant)
#define TC    4      // chunks per batch
#define MROWS 8192   // BATCH*NSEQ

__device__ __forceinline__ void gload16(const bf16* g, bf16* l) {
  __builtin_amdgcn_global_load_lds(
      (const __attribute__((address_space(1))) u32*)g,
      (__attribute__((address_space(3))) u32*)l, 16, 0, 0);
}

// ============ 128^2 core, minimal 2-phase (recurrence kernels; proven) ======

struct SmemTiles {
  alignas(16) bf16 As[2][128 * 32];
  alignas(16) bf16 Bs[2][128 * 32];
};

__device__ __forceinline__ void stage128(SmemTiles& sm, int bb, const bf16* A,
                                         int lda, const bf16* B, int ldb,
                                         int k0, int tid) {
#pragma unroll
  for (int it = 0; it < 2; ++it) {
    int c = it * 256 + tid;      // 16B chunk index, 512 chunks per tile
    int r = c >> 2;              // 4 chunks per 32-elem row
    int co = (c & 3) << 3;
    gload16(A + (size_t)r * lda + k0 + co, &sm.As[bb][c * 8]);
    gload16(B + (size_t)r * ldb + k0 + co, &sm.Bs[bb][c * 8]);
  }
}

__device__ __forceinline__ void gemm_core(SmemTiles& sm, const bf16* A, int lda,
                                          const bf16* B, int ldb, int K,
                                          f32x4 acc[4][4]) {
  const int tid = threadIdx.x;
  const int lane = tid & 63;
  const int wave = tid >> 6;
  const int wr = wave >> 1, wc = wave & 1;
  const int l15 = lane & 15, kl = lane >> 4;
  const int NT = K >> 5;
  if (NT <= 0) return;

  stage128(sm, 0, A, lda, B, ldb, 0, tid);
  __syncthreads();

  const int ao = (wr * 64 + l15) * 32 + kl * 8;
  const int bo = (wc * 64 + l15) * 32 + kl * 8;

  for (int t = 0; t < NT; ++t) {
    if (t + 1 < NT)
      stage128(sm, (t + 1) & 1, A, lda, B, ldb, (t + 1) * 32, tid);
    const bf16* Ab = sm.As[t & 1];
    const bf16* Bb = sm.Bs[t & 1];
    bf16x8 a[4], b[4];
#pragma unroll
    for (int m = 0; m < 4; ++m) a[m] = *(const bf16x8*)(Ab + ao + m * 16 * 32);
#pragma unroll
    for (int n = 0; n < 4; ++n) b[n] = *(const bf16x8*)(Bb + bo + n * 16 * 32);
    __builtin_amdgcn_s_setprio(1);
#pragma unroll
    for (int m = 0; m < 4; ++m)
#pragma unroll
      for (int n = 0; n < 4; ++n)
        acc[m][n] = __builtin_amdgcn_mfma_f32_16x16x32_bf16(a[m], b[n], acc[m][n], 0, 0, 0);
    __builtin_amdgcn_s_setprio(0);
    if (t + 1 < NT) __syncthreads();
  }
}

#define EPILOGUE_VARS                              \
  const int lane = threadIdx.x & 63;               \
  const int wave = threadIdx.x >> 6;               \
  const int wr = wave >> 1, wc = wave & 1;         \
  const int l15 = lane & 15, kl = lane >> 4;

// ============ 128x256 big-GEMM core: counted-vmcnt 2-deep (proven best) =====

struct SmemW {
  alignas(16) bf16 A[2][128 * 32];   // 8 slabs x 512 elems per buffer
  alignas(16) bf16 B[2][256 * 32];   // 16 slabs per buffer
};

__device__ __forceinline__ void stageW(SmemW& sm, int bb, const bf16* A,
                                       int lda, const bf16* B, int ldb,
                                       int k0, int wave, int lane) {
  const int r16 = lane & 15, c8 = lane >> 4;
  gload16(A + (size_t)(wave * 16 + r16) * lda + k0 + c8 * 8,
          &sm.A[bb][wave * 512 + lane * 8]);
#pragma unroll
  for (int j = 0; j < 2; ++j) {
    int nb = 2 * wave + j;
    gload16(B + (size_t)(nb * 16 + r16) * ldb + k0 + c8 * 8,
            &sm.B[bb][nb * 512 + lane * 8]);
  }
}

__device__ __forceinline__ void gemmW_core(SmemW& sm, const bf16* A, int lda,
                                           const bf16* B, int ldb, int K,
                                           f32x4 acc[4][4]) {
  const int tid = threadIdx.x;
  const int wave = tid >> 6, lane = tid & 63;
  const int wr = wave >> 2, wc = wave & 3;
  const int NT = K >> 5;
  if (NT <= 0) return;

  stageW(sm, 0, A, lda, B, ldb, 0, wave, lane);
  if (NT > 1) {
    stageW(sm, 1, A, lda, B, ldb, 32, wave, lane);
    asm volatile("s_waitcnt vmcnt(3)" ::: "memory");  // tile 0 resident (own)
  } else {
    asm volatile("s_waitcnt vmcnt(0)" ::: "memory");
  }
  __builtin_amdgcn_s_barrier();  // tile 0 resident for ALL waves

  const int aoff = wr * 2048 + lane * 8;  // slabs wr*4..+3
  const int boff = wc * 2048 + lane * 8;  // slabs wc*4..+3

  for (int t = 0; t < NT; ++t) {
    const bf16* Ab = sm.A[t & 1];
    const bf16* Bb = sm.B[t & 1];
    bf16x8 av[4], bv[4];
#pragma unroll
    for (int m = 0; m < 4; ++m) av[m] = *(const bf16x8*)&Ab[aoff + m * 512];
#pragma unroll
    for (int n = 0; n < 4; ++n) bv[n] = *(const bf16x8*)&Bb[boff + n * 512];
    asm volatile("s_waitcnt lgkmcnt(0)" ::: "memory");  // my reads done
    __builtin_amdgcn_s_barrier();                       // all waves' reads done
    if (t + 2 < NT)                                     // refill freed buffer
      stageW(sm, t & 1, A, lda, B, ldb, (t + 2) * 32, wave, lane);
    __builtin_amdgcn_s_setprio(1);
#pragma unroll
    for (int m = 0; m < 4; ++m)
#pragma unroll
      for (int n = 0; n < 4; ++n)
        acc[m][n] = __builtin_amdgcn_mfma_f32_16x16x32_bf16(av[m], bv[n],
                                                            acc[m][n], 0, 0, 0);
    __builtin_amdgcn_s_setprio(0);
    if (t + 1 < NT) {
      if (t + 2 < NT)
        asm volatile("s_waitcnt vmcnt(3)" ::: "memory");  // t+1 resident
      else
        asm volatile("s_waitcnt vmcnt(0)" ::: "memory");
      __builtin_amdgcn_s_barrier();
    }
  }
}

#define EPILOGUEW_VARS                             \
  const int lane = threadIdx.x & 63;               \
  const int wave = threadIdx.x >> 6;               \
  const int wr = wave >> 2, wc = wave & 3;         \
  const int l15 = lane & 15, kl = lane >> 4;

// T1: bijective XCD row-chunk swizzles.
// swzW: (8, 64) grids (k_final2). XCD i owns by in [8i,8i+8) x all 8 bx.
__device__ __forceinline__ void swzW(int& bx, int& by) {
  int lin = blockIdx.y * gridDim.x + blockIdx.x;   // 0..511
  int xcd = lin & 7, pos = lin >> 3;               // pos 0..63
  by = xcd * 8 + (pos >> 3);
  bx = pos & 7;
}
// swzF: (16, 64) grids (fused projections). XCD i owns by in [8i,8i+8) x all
// 16 bx -> A working set 8 x 0.5 MB = 4 MB = one L2 per XCD.
__device__ __forceinline__ void swzF(int& bx, int& by) {
  int lin = blockIdx.y * gridDim.x + blockIdx.x;   // 0..1023
  int xcd = lin & 7, pos = lin >> 3;               // pos 0..127
  by = xcd * 8 + (pos >> 4);
  bx = pos & 15;
}

// ---------------- elementwise kernels ----------------

__global__ __launch_bounds__(256) void k_f2b(const float* __restrict__ in,
                                             bf16* __restrict__ out) {
  int i = (blockIdx.x * 256 + threadIdx.x) * 8;
  float4 a = *(const float4*)(in + i);
  float4 b = *(const float4*)(in + i + 4);
  bf16x8 o;
  o[0] = (bf16)a.x; o[1] = (bf16)a.y; o[2] = (bf16)a.z; o[3] = (bf16)a.w;
  o[4] = (bf16)b.x; o[5] = (bf16)b.y; o[6] = (bf16)b.z; o[7] = (bf16)b.w;
  *(bf16x8*)(out + i) = o;
}

// convert two 2048x2048 fp32 weights into one contiguous bf16 buffer
__global__ __launch_bounds__(256) void k_f2b2(const float* __restrict__ in0,
                                              const float* __restrict__ in1,
                                              bf16* __restrict__ out) {
  int i = (blockIdx.x * 256 + threadIdx.x) * 8;
  const float* src = (i < D_ * D_) ? in0 : in1;
  int off = (i < D_ * D_) ? i : i - D_ * D_;
  float4 a = *(const float4*)(src + off);
  float4 b = *(const float4*)(src + off + 4);
  bf16x8 o;
  o[0] = (bf16)a.x; o[1] = (bf16)a.y; o[2] = (bf16)a.z; o[3] = (bf16)a.w;
  o[4] = (bf16)b.x; o[5] = (bf16)b.y; o[6] = (bf16)b.z; o[7] = (bf16)b.w;
  *(bf16x8*)(out + i) = o;
}

// fused prefix adds over the kv slots: s1 += s0 ; s2 += (s1+s0).
__global__ __launch_bounds__(256) void k_add2(bf16* __restrict__ s0,
                                              bf16* __restrict__ s1,
                                              bf16* __restrict__ s2) {
  size_t i = ((size_t)blockIdx.x * 256 + threadIdx.x) * 8;
  bf16x8 a = *(const bf16x8*)(s0 + i);
  bf16x8 b = *(const bf16x8*)(s1 + i);
  bf16x8 c = *(const bf16x8*)(s2 + i);
  bf16x8 o1, o2;
#pragma unroll
  for (int j = 0; j < 8; ++j) {
    float p = (float)a[j] + (float)b[j];
    o1[j] = (bf16)p;
    o2[j] = (bf16)((float)o1[j] + (float)c[j]);
  }
  *(bf16x8*)(s1 + i) = o1;
  *(bf16x8*)(s2 + i) = o2;
}

__global__ __launch_bounds__(256) void k_rms(const float* __restrict__ x,
                                             bf16* __restrict__ xn) {
  const int row = blockIdx.x;
  const int tid = threadIdx.x;
  const float* xr = x + (size_t)row * D_;
  float4 a = *(const float4*)(xr + tid * 8);
  float4 b = *(const float4*)(xr + tid * 8 + 4);
  float ss = a.x * a.x + a.y * a.y + a.z * a.z + a.w * a.w +
             b.x * b.x + b.y * b.y + b.z * b.z + b.w * b.w;
#pragma unroll
  for (int o = 32; o > 0; o >>= 1) ss += __shfl_xor(ss, o, 64);
  __shared__ float red[4];
  if ((tid & 63) == 0) red[tid >> 6] = ss;
  __syncthreads();
  float tot = red[0] + red[1] + red[2] + red[3];
  float sc = rsqrtf(tot * (1.f / D_) + 1.1920928955078125e-07f);
  bf16x8 o;
  o[0] = (bf16)(a.x * sc); o[1] = (bf16)(a.y * sc);
  o[2] = (bf16)(a.z * sc); o[3] = (bf16)(a.w * sc);
  o[4] = (bf16)(b.x * sc); o[5] = (bf16)(b.y * sc);
  o[6] = (bf16)(b.z * sc); o[7] = (bf16)(b.w * sc);
  *(bf16x8*)(xn + (size_t)row * D_ + tid * 8) = o;
}

// ---------------- fused pairwise projections (W-core + swzF) ----------------
// C = act(xn @ [W0;W1]^T): one launch covers TWO projections (N=4096).
// Grid (16, 64) = 1024 blocks -> 3 blocks/CU by LDS. Each 256-col block span
// lies entirely in one projection; epilogue branches block-uniformly.
// SMODE bit0: store normal [8192,2048]; bit1: store transposed [B][D][N]
// (packed bf16x4 along the row axis).

template <int ACT0, int SM0, int ACT1, int SM1>
__global__ __launch_bounds__(512, 4) void k_projF(const bf16* __restrict__ xn,
                                                  const bf16* __restrict__ Wcat,
                                                  bf16* __restrict__ Cn0,
                                                  bf16* __restrict__ Ct0,
                                                  bf16* __restrict__ Cn1,
                                                  bf16* __restrict__ Ct1) {
  __shared__ SmemW sm;
  int bx, by;
  swzF(bx, by);
  const int row0 = by * 128, col0 = bx * 256;
  f32x4 acc[4][4] = {};
  gemmW_core(sm, xn + (size_t)row0 * D_, D_, Wcat + (size_t)col0 * D_, D_, D_, acc);
  EPILOGUEW_VARS
  const int pid = col0 >> 11;          // 0: first projection, 1: second
  const int cb = (col0 & 2047);
#pragma unroll
  for (int m = 0; m < 4; ++m)
#pragma unroll
    for (int n = 0; n < 4; ++n) {
      const int rb = row0 + wr * 64 + m * 16 + kl * 4;  // 4 consecutive rows
      const int c = cb + wc * 64 + n * 16 + l15;
      bf16 ob[4];
      if (pid == 0) {
#pragma unroll
        for (int j = 0; j < 4; ++j) {
          float v = acc[m][n][j];
          if (ACT0 == 1) v = v / (1.f + __expf(-v));
          if (ACT0 == 2) v = 1.f / (1.f + __expf(-v));
          ob[j] = (bf16)v;
        }
        if (SM0 & 1) {
#pragma unroll
          for (int j = 0; j < 4; ++j) Cn0[(size_t)(rb + j) * D_ + c] = ob[j];
        }
        if (SM0 & 2) {
          bf16x4 tv = {ob[0], ob[1], ob[2], ob[3]};
          *(bf16x4*)&Ct0[((size_t)(rb >> 12) * D_ + c) * NSEQ + (rb & (NSEQ - 1))] = tv;
        }
      } else {
#pragma unroll
        for (int j = 0; j < 4; ++j) {
          float v = acc[m][n][j];
          if (ACT1 == 1) v = v / (1.f + __expf(-v));
          if (ACT1 == 2) v = 1.f / (1.f + __expf(-v));
          ob[j] = (bf16)v;
        }
        if (SM1 & 1) {
#pragma unroll
          for (int j = 0; j < 4; ++j) Cn1[(size_t)(rb + j) * D_ + c] = ob[j];
        }
        if (SM1 & 2) {
          bf16x4 tv = {ob[0], ob[1], ob[2], ob[3]};
          *(bf16x4*)&Ct1[((size_t)(rb >> 12) * D_ + c) * NSEQ + (rb & (NSEQ - 1))] = tv;
        }
      }
    }
}

// out = og @ Wp^T (fp32 store)
__global__ __launch_bounds__(512, 4) void k_final2(const bf16* __restrict__ og,
                                                   const bf16* __restrict__ Wp,
                                                   float* __restrict__ out) {
  __shared__ SmemW sm;
  int bx, by;
  swzW(bx, by);
  const int row0 = by * 128, col0 = bx * 256;
  f32x4 acc[4][4] = {};
  gemmW_core(sm, og + (size_t)row0 * D_, D_, Wp + (size_t)col0 * D_, D_, D_, acc);
  EPILOGUEW_VARS
#pragma unroll
  for (int m = 0; m < 4; ++m)
#pragma unroll
    for (int n = 0; n < 4; ++n)
#pragma unroll
      for (int j = 0; j < 4; ++j) {
        int r = row0 + wr * 64 + m * 16 + kl * 4 + j;
        int c = col0 + wc * 64 + n * 16 + l15;
        out[(size_t)r * D_ + c] = acc[m][n][j];
      }
}

// ---------------- chunked-recurrence kernels (128^2 core, R16-proven) -------

// s[z] = tril(q_t k_t^T), z = b*TC + t, chunk CH=1024.
__global__ __launch_bounds__(256) void k_scores(const bf16* __restrict__ q,
                                                const bf16* __restrict__ k,
                                                bf16* __restrict__ s) {
  const int z = blockIdx.z, b = z >> 2, t = z & 3;
  const int row0 = blockIdx.y * 128, col0 = blockIdx.x * 128;
  if (col0 > row0) return;  // strictly upper tile
  __shared__ SmemTiles sm;
  f32x4 acc[4][4] = {};
  gemm_core(sm, q + (size_t)(b * NSEQ + t * CH + row0) * D_, D_,
                k + (size_t)(b * NSEQ + t * CH + col0) * D_, D_, D_, acc);
  EPILOGUE_VARS
  bf16* sp = s + (size_t)z * CH * CH;
#pragma unroll
  for (int m = 0; m < 4; ++m)
#pragma unroll
    for (int n = 0; n < 4; ++n)
#pragma unroll
      for (int j = 0; j < 4; ++j) {
        int i = row0 + wr * 64 + m * 16 + kl * 4 + j;
        int jc = col0 + wc * 64 + n * 16 + l15;
        float v = (i >= jc) ? acc[m][n][j] : 0.f;
        sp[(size_t)i * CH + jc] = (bf16)v;
      }
}

// og[chunk rows] = s @ v  (intra-chunk; K trimmed to lower-tri extent).
// Chunk 0 gated here; inter-chunk pass skips t=0.
__global__ __launch_bounds__(256) void k_ointra(const bf16* __restrict__ s,
                                                const bf16* __restrict__ vT,
                                                const bf16* __restrict__ g,
                                                bf16* __restrict__ og) {
  __shared__ SmemTiles sm;
  const int z = blockIdx.z, b = z >> 2, t = z & 3;
  const int row0 = blockIdx.y * 128, col0 = blockIdx.x * 128;
  const int K = row0 + 128;
  f32x4 acc[4][4] = {};
  gemm_core(sm, s + (size_t)z * CH * CH + (size_t)row0 * CH, CH,
                vT + (size_t)b * D_ * NSEQ + (size_t)col0 * NSEQ + t * CH, NSEQ,
                K, acc);
  EPILOGUE_VARS
  const bool gate0 = (t == 0);
#pragma unroll
  for (int m = 0; m < 4; ++m)
#pragma unroll
    for (int n = 0; n < 4; ++n)
#pragma unroll
      for (int j = 0; j < 4; ++j) {
        int i = row0 + wr * 64 + m * 16 + kl * 4 + j;
        int c = col0 + wc * 64 + n * 16 + l15;
        size_t idx = (size_t)(b * NSEQ + t * CH + i) * D_ + c;
        float v = acc[m][n][j];
        if (gate0) v *= (float)g[idx];
        og[idx] = (bf16)v;
      }
}

// ALL per-chunk outer products in one parallel launch (pure write):
// kv_s[b][e][d] = sum_{j in chunk s} v[j][e] k[j][d], s in {0,1,2}, b in {0,1}.
__global__ __launch_bounds__(256) void k_update_all(const bf16* __restrict__ vT,
                                                    const bf16* __restrict__ kT,
                                                    bf16* __restrict__ kv01,
                                                    bf16* __restrict__ kv2) {
  __shared__ SmemTiles sm;
  const int z = blockIdx.z, s = z >> 1, b = z & 1;
  const int row0 = blockIdx.y * 128, col0 = blockIdx.x * 128;  // row=e, col=d
  f32x4 acc[4][4] = {};
  gemm_core(sm, vT + (size_t)b * D_ * NSEQ + (size_t)row0 * NSEQ + s * CH, NSEQ,
                kT + (size_t)b * D_ * NSEQ + (size_t)col0 * NSEQ + s * CH, NSEQ,
                CH, acc);
  EPILOGUE_VARS
  bf16* dst = (s < 2) ? kv01 + (size_t)(s * 2 + b) * D_ * D_
                      : kv2 + (size_t)b * D_ * D_;
#pragma unroll
  for (int m = 0; m < 4; ++m)
#pragma unroll
    for (int n = 0; n < 4; ++n)
#pragma unroll
      for (int j = 0; j < 4; ++j) {
        int e = row0 + wr * 64 + m * 16 + kl * 4 + j;
        int d = col0 + wc * 64 + n * 16 + l15;
        dst[(size_t)e * D_ + d] = (bf16)acc[m][n][j];
      }
}

// og = (og + q_t @ prefix_{t-1}^T) * g  for all t in {1,2,3}, both batches.
__global__ __launch_bounds__(256) void k_ointer_all(const bf16* __restrict__ q,
                                                    const bf16* __restrict__ kv01,
                                                    const bf16* __restrict__ kv2,
                                                    const bf16* __restrict__ g,
                                                    bf16* __restrict__ og) {
  __shared__ SmemTiles sm;
  const int z = blockIdx.z;             // 0..5
  const int t = (z >> 1) + 1, b = z & 1;
  const bf16* kv = (t <= 2) ? kv01 + (size_t)((t - 1) * 2 + b) * D_ * D_
                            : kv2 + (size_t)b * D_ * D_;
  const int row0 = blockIdx.y * 128, col0 = blockIdx.x * 128;
  f32x4 acc[4][4] = {};
  gemm_core(sm, q + (size_t)(b * NSEQ + t * CH + row0) * D_, D_,
                kv + (size_t)col0 * D_, D_, D_, acc);
  EPILOGUE_VARS
#pragma unroll
  for (int m = 0; m < 4; ++m)
#pragma unroll
    for (int n = 0; n < 4; ++n)
#pragma unroll
      for (int j = 0; j < 4; ++j) {
        int i = row0 + wr * 64 + m * 16 + kl * 4 + j;
        int c = col0 + wc * 64 + n * 16 + l15;
        size_t idx = (size_t)(b * NSEQ + t * CH + i) * D_ + c;
        float v = ((float)og[idx] + acc[m][n][j]) * (float)g[idx];
        og[idx] = (bf16)v;
      }
}

// ---------------- host launch ----------------
//
// Workspace plan (~145 MiB, proven): xn/og 32 | kT 32 | vT 32 |
// {k 32 -> kv01 32 (4 slots)} | shared 16 {Wcat -> s -> kv2 -> Wpb}.
// q,g live in d_out.  Projections fused pairwise ([Wq;Wk], [Wv;Wg]) on the
// W-core with the swzF XCD row-band swizzle (R12 fusion + R15 swizzle,
// first time combined).

extern "C" void kernel_launch(void* const* d_in, const int* in_sizes, int n_in,
                              void* d_out, int out_size, void* d_ws, size_t ws_size,
                              hipStream_t stream) {
  (void)in_sizes; (void)n_in; (void)out_size; (void)ws_size;
  const float* x  = (const float*)d_in[0];
  const float* Wq = (const float*)d_in[1];
  const float* Wk = (const float*)d_in[2];
  const float* Wv = (const float*)d_in[3];
  const float* Wg = (const float*)d_in[4];
  const float* Wp = (const float*)d_in[5];
  float* out = (float*)d_out;

  char* p = (char*)d_ws;
  auto take = [&](size_t bytes) {
    char* r = p;
    p += (bytes + 255) & ~(size_t)255;
    return r;
  };
  const size_t MD2 = (size_t)MROWS * D_ * 2;
  const size_t KV1 = (size_t)D_ * D_;          // elems per kv slot

  bf16* xn  = (bf16*)take(MD2);                        // reused as og
  bf16* kT  = (bf16*)take(MD2);
  bf16* vT  = (bf16*)take(MD2);
  char* kregion = take(MD2);                           // k, then kv01 (4 slots)
  bf16* k    = (bf16*)kregion;
  bf16* kv01 = (bf16*)kregion;
  char* shared = take((size_t)BATCH * TC * CH * CH * 2);  // 16 MiB region
  bf16* Wcat = (bf16*)shared;    // [4096,2048] bf16, then s, then kv2, then Wp
  bf16* s    = (bf16*)shared;
  bf16* kv2  = (bf16*)shared;
  bf16* og = xn;

  bf16* q = (bf16*)d_out;
  bf16* g = (bf16*)d_out + (size_t)MROWS * D_;

  dim3 gpF(2 * D_ / 256, MROWS / 128);  // (16, 64) = 1024 blocks, 3/CU
  dim3 gpW(D_ / 256, MROWS / 128);      // (8, 64)  = 512 blocks, 2/CU

  k_rms<<<MROWS, 256, 0, stream>>>(x, xn);

  // q = silu(xn Wq^T) -> normal; k = silu(xn Wk^T) -> normal + transposed
  k_f2b2<<<2 * (D_ * D_) / 2048, 256, 0, stream>>>(Wq, Wk, Wcat);
  k_projF<1, 1, 1, 3><<<gpF, 512, 0, stream>>>(xn, Wcat, q, (bf16*)nullptr,
                                               k, kT);
  // v = silu(xn Wv^T) -> transposed only; g = sigmoid(xn Wg^T) -> normal
  k_f2b2<<<2 * (D_ * D_) / 2048, 256, 0, stream>>>(Wv, Wg, Wcat);
  k_projF<1, 2, 2, 1><<<gpF, 512, 0, stream>>>(xn, Wcat, (bf16*)nullptr, vT,
                                               g, (bf16*)nullptr);

  // intra-chunk: masked scores (lower-tri tiles only) then s @ v
  // (chunk 0 gated inside ointra; no inter-chunk pass for t=0)
  k_scores<<<dim3(CH / 128, CH / 128, BATCH * TC), 256, 0, stream>>>(q, k, s);
  k_ointra<<<dim3(D_ / 128, CH / 128, BATCH * TC), 256, 0, stream>>>(s, vT, g, og);

  // k and s dead -> their regions hold the 6 kv slots. All outer products
  // in ONE launch (grid 1536), then one fused prefix-add, then all
  // inter-chunk GEMMs in ONE launch (grid 768).
  k_update_all<<<dim3(D_ / 128, D_ / 128, 6), 256, 0, stream>>>(vT, kT, kv01, kv2);
  k_add2<<<(2 * D_ * D_) / 2048, 256, 0, stream>>>(kv01, kv01 + 2 * KV1, kv2);
  k_ointer_all<<<dim3(D_ / 128, CH / 128, 6), 256, 0, stream>>>(q, kv01, kv2,
                                                                g, og);

  // kv slots dead; shared region hosts the bf16 Wp
  bf16* Wpb = (bf16*)shared;
  k_f2b<<<(D_ * D_) / 2048, 256, 0, stream>>>(Wp, Wpb);
  k_final2<<<gpW, 512, 0, stream>>>(og, Wpb, out);
}